// Round 1
// baseline (117.259 us; speedup 1.0000x reference)
//
#include <hip/hip_runtime.h>

#define DEV __device__ __forceinline__

typedef __attribute__((ext_vector_type(8))) short bf16x8;
typedef __attribute__((ext_vector_type(4))) short bf16x4;
typedef __attribute__((ext_vector_type(4))) float f32x4;
typedef __attribute__((ext_vector_type(4))) unsigned int u32x4;

constexpr int Bb = 8;
constexpr int Nn = 1024;
constexpr int DIMm = 512;
constexpr int Hh = 8;
constexpr int Dh = 64;
constexpr int Mm = Bb * Nn;  // 8192
constexpr float LN10K = 9.210340371976184f;  // ln(10000)

DEV short f2bf(float f) {
  unsigned int u = __float_as_uint(f);
  u += 0x7fffu + ((u >> 16) & 1u);  // RNE
  return (short)(u >> 16);
}

DEV bf16x8 comb(bf16x4 lo, bf16x4 hi) {
  bf16x8 r;
  r[0] = lo[0]; r[1] = lo[1]; r[2] = lo[2]; r[3] = lo[3];
  r[4] = hi[0]; r[5] = hi[1]; r[6] = hi[2]; r[7] = hi[3];
  return r;
}

DEV f32x4 mfma16(bf16x8 a, bf16x8 b, f32x4 c) {
  return __builtin_amdgcn_mfma_f32_16x16x32_bf16(a, b, c, 0, 0, 0);
}

// ---------------------------------------------------------------------------
// prep: x -> bf16 ; w_qkv -> transposed bf16 [1536][512] ; w_out -> [512][512]
// ---------------------------------------------------------------------------
__global__ void prep_kernel(const float* __restrict__ x, const float* __restrict__ wq,
                            const float* __restrict__ wo, short* __restrict__ x_bf,
                            short* __restrict__ wqkvT, short* __restrict__ woutT) {
  int stride = gridDim.x * blockDim.x;
  int t = blockIdx.x * blockDim.x + threadIdx.x;
  for (int i = t; i < Mm * DIMm / 4; i += stride) {
    float4 v = ((const float4*)x)[i];
    bf16x4 o;
    o[0] = f2bf(v.x); o[1] = f2bf(v.y); o[2] = f2bf(v.z); o[3] = f2bf(v.w);
    *(bf16x4*)(x_bf + (size_t)i * 4) = o;
  }
  for (int i = t; i < 1536 * 512; i += stride) {
    int n = i >> 9, k = i & 511;
    wqkvT[i] = f2bf(wq[(size_t)k * 1536 + n]);
  }
  for (int i = t; i < 512 * 512; i += stride) {
    int n = i >> 9, k = i & 511;
    woutT[i] = f2bf(wo[(size_t)k * 512 + n]);
  }
}

// ---------------------------------------------------------------------------
// GEMM: A[Mx512] bf16 row-major, Bt[Ncols x 512] bf16 (pre-transposed).
// QKV==1: epilogue applies RoPE+scale, writes qr/kr [b][h][n][d], vt [b][h][d][n]
// QKV==0: plain f32 store to outF [Mx512]
// MFMA 16x16x32 bf16, split-4 k-mapping assumption:
//   A/B frag regs 0-3 : k = 4*(lane>>4)+r ; regs 4-7 : k = 16+4*(lane>>4)+r
//   C/D: col = lane&15, row = 4*(lane>>4)+reg   [verified m89]
// ---------------------------------------------------------------------------
template <int QKV>
__global__ __launch_bounds__(256) void gemm_k(const short* __restrict__ A,
                                              const short* __restrict__ Bt,
                                              float* __restrict__ outF,
                                              short* __restrict__ qr,
                                              short* __restrict__ kr,
                                              short* __restrict__ vt) {
  __shared__ short Al[128][40];  // pad 8 bf16
  __shared__ short Bl[128][40];
  const int tid = threadIdx.x;
  const int lane = tid & 63;
  const int wid = tid >> 6;
  const int wm = wid >> 1, wn = wid & 1;  // 2x2 waves, 64x64 each
  const int li = lane & 15, g4 = (lane >> 4) << 2;
  const int m0 = blockIdx.x * 128, n0 = blockIdx.y * 128;

  f32x4 zero4 = {0.f, 0.f, 0.f, 0.f};
  f32x4 acc[4][4];
#pragma unroll
  for (int i = 0; i < 4; ++i)
#pragma unroll
    for (int j = 0; j < 4; ++j) acc[i][j] = zero4;

  for (int kt = 0; kt < 512; kt += 32) {
#pragma unroll
    for (int p = 0; p < 2; ++p) {
      int e = (tid + p * 256) * 8;
      int r = e >> 5, c = e & 31;
      *(u32x4*)(&Al[r][c]) = *(const u32x4*)(A + (size_t)(m0 + r) * 512 + kt + c);
      *(u32x4*)(&Bl[r][c]) = *(const u32x4*)(Bt + (size_t)(n0 + r) * 512 + kt + c);
    }
    __syncthreads();
    bf16x8 af[4], bfr[4];
#pragma unroll
    for (int mt = 0; mt < 4; ++mt) {
      int row = wm * 64 + mt * 16 + li;
      af[mt] = comb(*(const bf16x4*)(&Al[row][g4]), *(const bf16x4*)(&Al[row][16 + g4]));
    }
#pragma unroll
    for (int nt = 0; nt < 4; ++nt) {
      int row = wn * 64 + nt * 16 + li;
      bfr[nt] = comb(*(const bf16x4*)(&Bl[row][g4]), *(const bf16x4*)(&Bl[row][16 + g4]));
    }
#pragma unroll
    for (int mt = 0; mt < 4; ++mt)
#pragma unroll
      for (int nt = 0; nt < 4; ++nt)
        acc[mt][nt] = mfma16(af[mt], bfr[nt], acc[mt][nt]);
    __syncthreads();
  }

  if (QKV == 0) {
#pragma unroll
    for (int mt = 0; mt < 4; ++mt) {
      int mb = m0 + wm * 64 + mt * 16 + g4;
#pragma unroll
      for (int nt = 0; nt < 4; ++nt) {
        int c = n0 + wn * 64 + nt * 16 + li;
#pragma unroll
        for (int r = 0; r < 4; ++r) outF[(size_t)(mb + r) * 512 + c] = acc[mt][nt][r];
      }
    }
  } else {
    const int sec = n0 >> 9;  // 0=q 1=k 2=v (uniform per block)
#pragma unroll
    for (int mt = 0; mt < 4; ++mt) {
      int mb = m0 + wm * 64 + mt * 16 + g4;
      int b_ = mb >> 10;
      int nb = mb & 1023;
#pragma unroll
      for (int nt = 0; nt < 4; ++nt) {
        int c = n0 + wn * 64 + nt * 16 + li;
        int cs = c & 511;
        int hh = cs >> 6, d = cs & 63;
        if (sec == 2) {
          bf16x4 pk;
#pragma unroll
          for (int r = 0; r < 4; ++r) pk[r] = f2bf(acc[mt][nt][r]);
          *(bf16x4*)(vt + ((size_t)(b_ * Hh + hh) * Dh + d) * Nn + nb) = pk;
        } else {
          float invf = __expf(-(float)(d & ~1) * (LN10K / 64.f));
          short* dst = (sec == 0 ? qr : kr) + ((size_t)(b_ * Hh + hh) * Nn + nb) * Dh + d;
#pragma unroll
          for (int r = 0; r < 4; ++r) {
            float v0 = acc[mt][nt][r];
            float vp = __shfl_xor(v0, 1, 64);  // pair partner (adjacent col)
            float fr = (float)(nb + r) * invf;
            float sn, cs2;
            __sincosf(fr, &sn, &cs2);
            float rot = (d & 1) ? vp : -vp;
            float res = v0 * cs2 + rot * sn;
            if (sec == 0) res *= 0.125f;  // Dh^-0.5
            dst[(size_t)r * Dh] = f2bf(res);
          }
        }
      }
    }
  }
}

// ---------------------------------------------------------------------------
// Flash attention, swapped-QK trick: compute S^T = mfma(K, Q), so each lane
// owns one q-row (i = lane&15); softmax in-register; P feeds PV A-operand
// directly. 4 waves x 16 q-rows = 64 q-rows per block; K/V tiles (64) in LDS.
// ---------------------------------------------------------------------------
__global__ __launch_bounds__(256) void attn_k(const short* __restrict__ qr,
                                              const short* __restrict__ kr,
                                              const short* __restrict__ vt,
                                              const float* __restrict__ bias,
                                              short* __restrict__ ao) {
  __shared__ short Kl[64][72];  // K tile  [j][d]
  __shared__ short Vl[64][72];  // V^T tile [d][j]
  const int tid = threadIdx.x, lane = tid & 63, w = tid >> 6;
  const int li = lane & 15, g4 = (lane >> 4) << 2;
  const int bh = blockIdx.y, h = bh & 7, b_ = bh >> 3;
  const int i0 = blockIdx.x * 64;
  const int iq = i0 + w * 16 + li;  // this lane's q row

  const short* qrow = qr + ((size_t)bh * Nn + iq) * Dh;
  bf16x8 qf[2];
#pragma unroll
  for (int kk = 0; kk < 2; ++kk)
    qf[kk] = comb(*(const bf16x4*)(qrow + kk * 32 + g4),
                  *(const bf16x4*)(qrow + kk * 32 + 16 + g4));

  const short* Kb = kr + (size_t)bh * Nn * Dh;
  const short* Vb = vt + (size_t)bh * Dh * Nn;
  const float* brow = bias + ((size_t)h * Nn + iq) * Nn;

  float m_run = -1e30f, l_run = 0.f;
  f32x4 zero4 = {0.f, 0.f, 0.f, 0.f};
  f32x4 acc[4];
#pragma unroll
  for (int i = 0; i < 4; ++i) acc[i] = zero4;

  for (int j0 = 0; j0 < Nn; j0 += 64) {
#pragma unroll
    for (int pp = 0; pp < 2; ++pp) {
      int e = (tid + pp * 256) * 8;
      int r = e >> 6, c = e & 63;
      *(u32x4*)(&Kl[r][c]) = *(const u32x4*)(Kb + (size_t)(j0 + r) * Dh + c);
      *(u32x4*)(&Vl[r][c]) = *(const u32x4*)(Vb + (size_t)r * Nn + j0 + c);
    }
    __syncthreads();

    // S^T frags: lane holds i=li, j = js*16 + g4 + r
    f32x4 s[4];
#pragma unroll
    for (int js = 0; js < 4; ++js) {
      f32x4 sa = zero4;
#pragma unroll
      for (int kk = 0; kk < 2; ++kk) {
        bf16x8 kf = comb(*(const bf16x4*)(&Kl[js * 16 + li][kk * 32 + g4]),
                         *(const bf16x4*)(&Kl[js * 16 + li][kk * 32 + 16 + g4]));
        sa = mfma16(kf, qf[kk], sa);
      }
      f32x4 bb = *(const f32x4*)(brow + j0 + js * 16 + g4);
      s[js] = sa + bb;
    }
    // online softmax (per q-row; 4 replicas across lane groups)
    float mx = -1e30f;
#pragma unroll
    for (int js = 0; js < 4; ++js)
#pragma unroll
      for (int r = 0; r < 4; ++r) mx = fmaxf(mx, s[js][r]);
    mx = fmaxf(mx, __shfl_xor(mx, 16, 64));
    mx = fmaxf(mx, __shfl_xor(mx, 32, 64));
    float m_new = fmaxf(m_run, mx);
    float scale = __expf(m_run - m_new);
    float rs = 0.f;
#pragma unroll
    for (int js = 0; js < 4; ++js)
#pragma unroll
      for (int r = 0; r < 4; ++r) {
        float p = __expf(s[js][r] - m_new);
        s[js][r] = p;
        rs += p;
      }
    rs += __shfl_xor(rs, 16, 64);
    rs += __shfl_xor(rs, 32, 64);
    l_run = l_run * scale + rs;
    m_run = m_new;
    // rescale O-acc: acc rows are i = g4 + r; scale lives at lane i
    float fs[4];
#pragma unroll
    for (int r = 0; r < 4; ++r) fs[r] = __shfl(scale, g4 + r, 64);
#pragma unroll
    for (int dt = 0; dt < 4; ++dt)
#pragma unroll
      for (int r = 0; r < 4; ++r) acc[dt][r] *= fs[r];
    // P -> bf16 A-frags (regs 0-3 = js even, regs 4-7 = js odd)
    bf16x8 pf[2];
#pragma unroll
    for (int kk = 0; kk < 2; ++kk) {
      bf16x8 t;
#pragma unroll
      for (int r = 0; r < 4; ++r) {
        t[r] = f2bf(s[2 * kk][r]);
        t[4 + r] = f2bf(s[2 * kk + 1][r]);
      }
      pf[kk] = t;
    }
    // PV
#pragma unroll
    for (int dt = 0; dt < 4; ++dt) {
#pragma unroll
      for (int kk = 0; kk < 2; ++kk) {
        bf16x8 vf = comb(*(const bf16x4*)(&Vl[dt * 16 + li][kk * 32 + g4]),
                         *(const bf16x4*)(&Vl[dt * 16 + li][kk * 32 + 16 + g4]));
        acc[dt] = mfma16(pf[kk], vf, acc[dt]);
      }
    }
    __syncthreads();
  }
  // finalize: rows i = g4+r, 1/l lives at lane i
  float rl = 1.f / l_run;
  float fr[4];
#pragma unroll
  for (int r = 0; r < 4; ++r) fr[r] = __shfl(rl, g4 + r, 64);
#pragma unroll
  for (int dt = 0; dt < 4; ++dt)
#pragma unroll
    for (int r = 0; r < 4; ++r) {
      int i_ = i0 + w * 16 + g4 + r;
      ao[((size_t)(b_ * Nn + i_)) * 512 + h * 64 + dt * 16 + li] = f2bf(acc[dt][r] * fr[r]);
    }
}

// ---------------------------------------------------------------------------
extern "C" void kernel_launch(void* const* d_in, const int* in_sizes, int n_in,
                              void* d_out, int out_size, void* d_ws, size_t ws_size,
                              hipStream_t stream) {
  const float* x = (const float*)d_in[0];
  const float* pb = (const float*)d_in[1];
  const float* wq = (const float*)d_in[2];
  const float* wo = (const float*)d_in[3];
  float* out = (float*)d_out;

  short* w = (short*)d_ws;
  short* x_bf = w;  w += (size_t)Mm * DIMm;      // 8 MB
  short* wqkvT = w; w += 1536 * 512;             // 1.5 MB
  short* woutT = w; w += 512 * 512;              // 0.5 MB
  short* qr = w;    w += (size_t)Mm * DIMm;      // 8 MB
  short* kr = w;    w += (size_t)Mm * DIMm;      // 8 MB
  short* vt = w;    w += (size_t)Mm * DIMm;      // 8 MB
  short* ao = x_bf;  // reuse: x_bf dead after qkv GEMM

  prep_kernel<<<1024, 256, 0, stream>>>(x, wq, wo, x_bf, wqkvT, woutT);
  gemm_k<1><<<dim3(64, 12), 256, 0, stream>>>(x_bf, wqkvT, nullptr, qr, kr, vt);
  attn_k<<<dim3(16, 64), 256, 0, stream>>>(qr, kr, vt, pb, ao);
  gemm_k<0><<<dim3(64, 4), 256, 0, stream>>>(ao, woutT, out, nullptr, nullptr, nullptr);
}